// Round 1
// baseline (1196.373 us; speedup 1.0000x reference)
//
#include <hip/hip_runtime.h>

// GIN 2-layer: agg = segment_sum(x[src], dst); h = relu((x+agg)@Wa^T+ba) @ Wb^T + bb
// N=100000, E=1600000, D=128. fp32 throughout (round 1: correctness baseline).

#define WS_ALIGN(x) (((x) + 255) & ~(size_t)255)

// ---------- CSR build ----------
__global__ void hist_kernel(const int* __restrict__ dst, int* __restrict__ deg, int E) {
  int e = blockIdx.x * blockDim.x + threadIdx.x;
  if (e < E) atomicAdd(&deg[dst[e]], 1);
}

// single block, 1024 threads, 8 elems/thread per chunk
__global__ void scan_kernel(const int* __restrict__ deg, int* __restrict__ rowptr,
                            int* __restrict__ cursor, int n) {
  __shared__ int buf[1024];
  __shared__ int carry_s;
  int t = threadIdx.x;
  if (t == 0) carry_s = 0;
  __syncthreads();
  for (int base = 0; base < n; base += 8192) {
    int i0 = base + t * 8;
    int v[8];
#pragma unroll
    for (int q = 0; q < 8; q++) { int i = i0 + q; v[q] = (i < n) ? deg[i] : 0; }
    int s = 0;
#pragma unroll
    for (int q = 0; q < 8; q++) s += v[q];
    buf[t] = s;
    __syncthreads();
    for (int off = 1; off < 1024; off <<= 1) {
      int add = (t >= off) ? buf[t - off] : 0;
      __syncthreads();
      buf[t] += add;
      __syncthreads();
    }
    int run = buf[t] - s + carry_s;  // exclusive prefix for this thread's first elem
#pragma unroll
    for (int q = 0; q < 8; q++) {
      int i = i0 + q;
      if (i < n) { rowptr[i] = run; cursor[i] = run; }
      run += v[q];
    }
    __syncthreads();
    if (t == 1023) carry_s += buf[1023];
    __syncthreads();
  }
  if (t == 0) rowptr[n] = carry_s;
}

__global__ void scatter_kernel(const int* __restrict__ src, const int* __restrict__ dst,
                               int* __restrict__ cursor, int* __restrict__ srt, int E) {
  int e = blockIdx.x * blockDim.x + threadIdx.x;
  if (e < E) {
    int d = dst[e];
    int p = atomicAdd(&cursor[d], 1);
    srt[p] = src[e];
  }
}

// ---------- aggregation: out[i] = X[i] + sum_{p in row i} X[srt[p]] ----------
// one wave per node; lane owns 2 consecutive floats (float2), row = 512 B coalesced.
__global__ void aggregate_kernel(const float* __restrict__ X, const int* __restrict__ rowptr,
                                 const int* __restrict__ srt, float* __restrict__ out, int n) {
  int w = blockIdx.x * 4 + (threadIdx.x >> 6);
  int lane = threadIdx.x & 63;
  if (w >= n) return;
  const float2* Xv = (const float2*)X;
  float2 acc = Xv[(size_t)w * 64 + lane];
  int p = rowptr[w], end = rowptr[w + 1];
  for (; p + 4 <= end; p += 4) {
    int s0 = srt[p], s1 = srt[p + 1], s2 = srt[p + 2], s3 = srt[p + 3];
    float2 v0 = Xv[(size_t)s0 * 64 + lane];
    float2 v1 = Xv[(size_t)s1 * 64 + lane];
    float2 v2 = Xv[(size_t)s2 * 64 + lane];
    float2 v3 = Xv[(size_t)s3 * 64 + lane];
    acc.x += v0.x + v1.x + v2.x + v3.x;
    acc.y += v0.y + v1.y + v2.y + v3.y;
  }
  for (; p < end; ++p) {
    int s = srt[p];
    float2 v = Xv[(size_t)s * 64 + lane];
    acc.x += v.x;
    acc.y += v.y;
  }
  ((float2*)out)[(size_t)w * 64 + lane] = acc;
}

// ---------- GEMM: C[i][j] = act( sum_k A[i][k]*W[j][k] + bias[j] ) ----------
// block: 64 rows x 128 cols; thread: 4 rows x 8 cols; W staged in LDS (64 KB).
// In-place safe: each thread reads only its own 4 output rows.
template <int RELU>
__global__ __launch_bounds__(256) void gemm_kernel(const float* A, const float* __restrict__ W,
                                                   const float* __restrict__ bias, float* C,
                                                   int n) {
  __shared__ __align__(16) float Ws[16384];
  for (int idx = threadIdx.x; idx < 4096; idx += 256)
    ((float4*)Ws)[idx] = ((const float4*)W)[idx];
  __syncthreads();

  int t = threadIdx.x;
  int tx = t & 15;   // row group
  int ty = t >> 4;   // col group
  int r0 = blockIdx.x * 64 + tx * 4;
  int j0 = ty * 8;
  int krot = (ty & 3) * 4;  // rotate k start per ty -> avoids 4-way LDS bank conflict

  float acc[4][8];
#pragma unroll
  for (int i = 0; i < 4; i++)
#pragma unroll
    for (int j = 0; j < 8; j++) acc[i][j] = 0.f;

  if (r0 + 3 < n) {
    for (int kk = 0; kk < 128; kk += 4) {
      int k = (krot + kk) & 127;
      float4 a[4];
#pragma unroll
      for (int i = 0; i < 4; i++)
        a[i] = *(const float4*)&A[(size_t)(r0 + i) * 128 + k];
      float4 wv[8];
#pragma unroll
      for (int j = 0; j < 8; j++)
        wv[j] = *(const float4*)&Ws[(j0 + j) * 128 + k];
#pragma unroll
      for (int i = 0; i < 4; i++)
#pragma unroll
        for (int j = 0; j < 8; j++)
          acc[i][j] += a[i].x * wv[j].x + a[i].y * wv[j].y + a[i].z * wv[j].z + a[i].w * wv[j].w;
    }
#pragma unroll
    for (int i = 0; i < 4; i++) {
      float o[8];
#pragma unroll
      for (int j = 0; j < 8; j++) {
        float v = acc[i][j] + bias[j0 + j];
        o[j] = RELU ? fmaxf(v, 0.f) : v;
      }
      *(float4*)&C[(size_t)(r0 + i) * 128 + j0] = make_float4(o[0], o[1], o[2], o[3]);
      *(float4*)&C[(size_t)(r0 + i) * 128 + j0 + 4] = make_float4(o[4], o[5], o[6], o[7]);
    }
  } else {
    for (int kk = 0; kk < 128; kk += 4) {
      int k = (krot + kk) & 127;
      float4 a[4];
#pragma unroll
      for (int i = 0; i < 4; i++)
        a[i] = (r0 + i < n) ? *(const float4*)&A[(size_t)(r0 + i) * 128 + k]
                            : make_float4(0.f, 0.f, 0.f, 0.f);
      float4 wv[8];
#pragma unroll
      for (int j = 0; j < 8; j++)
        wv[j] = *(const float4*)&Ws[(j0 + j) * 128 + k];
#pragma unroll
      for (int i = 0; i < 4; i++)
#pragma unroll
        for (int j = 0; j < 8; j++)
          acc[i][j] += a[i].x * wv[j].x + a[i].y * wv[j].y + a[i].z * wv[j].z + a[i].w * wv[j].w;
    }
#pragma unroll
    for (int i = 0; i < 4; i++) {
      if (r0 + i >= n) continue;
      float o[8];
#pragma unroll
      for (int j = 0; j < 8; j++) {
        float v = acc[i][j] + bias[j0 + j];
        o[j] = RELU ? fmaxf(v, 0.f) : v;
      }
      *(float4*)&C[(size_t)(r0 + i) * 128 + j0] = make_float4(o[0], o[1], o[2], o[3]);
      *(float4*)&C[(size_t)(r0 + i) * 128 + j0 + 4] = make_float4(o[4], o[5], o[6], o[7]);
    }
  }
}

extern "C" void kernel_launch(void* const* d_in, const int* in_sizes, int n_in,
                              void* d_out, int out_size, void* d_ws, size_t ws_size,
                              hipStream_t stream) {
  const float* x   = (const float*)d_in[0];
  const int*   ei  = (const int*)d_in[1];
  const float* w0a = (const float*)d_in[2];
  const float* b0a = (const float*)d_in[3];
  const float* w0b = (const float*)d_in[4];
  const float* b0b = (const float*)d_in[5];
  const float* w1a = (const float*)d_in[6];
  const float* b1a = (const float*)d_in[7];
  const float* w1b = (const float*)d_in[8];
  const float* b1b = (const float*)d_in[9];
  float* out = (float*)d_out;

  int n = in_sizes[0] / 128;   // 100000
  int E = in_sizes[1] / 2;     // 1600000
  const int* src = ei;
  const int* dst = ei + E;

  char* w = (char*)d_ws;
  int* deg = (int*)w;    w += WS_ALIGN((size_t)(n + 1) * 4);
  int* rowptr = (int*)w; w += WS_ALIGN((size_t)(n + 1) * 4);
  int* cursor = (int*)w; w += WS_ALIGN((size_t)(n + 1) * 4);
  int* srt = (int*)w;    w += WS_ALIGN((size_t)E * 4);
  float* B1 = (float*)w; // n*128 floats (51.2 MB)

  // ---- CSR build (shared by both layers) ----
  hipMemsetAsync(deg, 0, (size_t)(n + 1) * 4, stream);
  hist_kernel<<<(E + 255) / 256, 256, 0, stream>>>(dst, deg, E);
  scan_kernel<<<1, 1024, 0, stream>>>(deg, rowptr, cursor, n);
  scatter_kernel<<<(E + 255) / 256, 256, 0, stream>>>(src, dst, cursor, srt, E);

  int agg_grid = (n + 3) / 4;
  int gemm_grid = (n + 63) / 64;

  // ---- layer 1 ----
  aggregate_kernel<<<agg_grid, 256, 0, stream>>>(x, rowptr, srt, B1, n);
  gemm_kernel<1><<<gemm_grid, 256, 0, stream>>>(B1, w0a, b0a, B1, n);
  gemm_kernel<0><<<gemm_grid, 256, 0, stream>>>(B1, w0b, b0b, B1, n);

  // ---- layer 2 ----
  aggregate_kernel<<<agg_grid, 256, 0, stream>>>(B1, rowptr, srt, out, n);
  gemm_kernel<1><<<gemm_grid, 256, 0, stream>>>(out, w1a, b1a, out, n);
  gemm_kernel<0><<<gemm_grid, 256, 0, stream>>>(out, w1b, b1b, out, n);
}

// Round 2
// 527.392 us; speedup vs baseline: 2.2685x; 2.2685x over previous
//
#include <hip/hip_runtime.h>

// GIN 2-layer, N=100000, E=1600000, D=128.
// R2: multi-block scan; bf16 activations (fp32 accumulate); fused per-layer
// MLP (two 128x128 linears) via mfma_f32_16x16x32_bf16 with LDS-swizzled W.

typedef __attribute__((ext_vector_type(8))) short bf16x8;
typedef __attribute__((ext_vector_type(4))) float floatx4;

#define WS_ALIGN(x) (((x) + 255) & ~(size_t)255)

__device__ __forceinline__ unsigned short f2b(float f) {  // RTNE fp32->bf16
  unsigned u = __builtin_bit_cast(unsigned, f);
  u = (u + 0x7FFF + ((u >> 16) & 1)) >> 16;
  return (unsigned short)u;
}
__device__ __forceinline__ float b2f(unsigned u16) {  // low 16 bits = bf16
  return __builtin_bit_cast(float, u16 << 16);
}

// ---------- CSR build ----------
__global__ void hist_kernel(const int* __restrict__ dst, int* __restrict__ deg, int E) {
  int e = blockIdx.x * blockDim.x + threadIdx.x;
  if (e < E) atomicAdd(&deg[dst[e]], 1);
}

__global__ void scan_partial(const int* __restrict__ deg, int* __restrict__ partial, int n) {
  __shared__ int red[1024];
  int t = threadIdx.x;
  int i0 = blockIdx.x * 8192 + t * 8;
  int s = 0;
#pragma unroll
  for (int q = 0; q < 8; q++) { int i = i0 + q; s += (i < n) ? deg[i] : 0; }
  red[t] = s;
  __syncthreads();
  for (int off = 512; off > 0; off >>= 1) {
    if (t < off) red[t] += red[t + off];
    __syncthreads();
  }
  if (t == 0) partial[blockIdx.x] = red[0];
}

__global__ void scan_carry(int* __restrict__ partial, int nb) {
  int run = 0;
  for (int i = 0; i < nb; i++) { int v = partial[i]; partial[i] = run; run += v; }
  partial[nb] = run;
}

__global__ void scan_final(const int* __restrict__ deg, const int* __restrict__ partial,
                           int* __restrict__ rowptr, int* __restrict__ cursor, int n) {
  __shared__ int buf[1024];
  int t = threadIdx.x;
  int i0 = blockIdx.x * 8192 + t * 8;
  int v[8];
#pragma unroll
  for (int q = 0; q < 8; q++) { int i = i0 + q; v[q] = (i < n) ? deg[i] : 0; }
  int s = 0;
#pragma unroll
  for (int q = 0; q < 8; q++) s += v[q];
  buf[t] = s;
  __syncthreads();
  for (int off = 1; off < 1024; off <<= 1) {
    int add = (t >= off) ? buf[t - off] : 0;
    __syncthreads();
    buf[t] += add;
    __syncthreads();
  }
  int run = buf[t] - s + partial[blockIdx.x];
#pragma unroll
  for (int q = 0; q < 8; q++) {
    int i = i0 + q;
    if (i < n) { rowptr[i] = run; cursor[i] = run; }
    run += v[q];
  }
  if (blockIdx.x == gridDim.x - 1 && t == 1023) rowptr[n] = partial[gridDim.x];
}

__global__ void scatter_kernel(const int* __restrict__ src, const int* __restrict__ dst,
                               int* __restrict__ cursor, int* __restrict__ srt, int E) {
  int e = blockIdx.x * blockDim.x + threadIdx.x;
  if (e < E) {
    int d = dst[e];
    int p = atomicAdd(&cursor[d], 1);
    srt[p] = src[e];
  }
}

// ---------- fp32 -> bf16 convert ----------
__global__ void cvt_kernel(const float* __restrict__ x, unsigned short* __restrict__ xb, int n4) {
  int i = blockIdx.x * blockDim.x + threadIdx.x;
  if (i < n4) {
    float4 v = ((const float4*)x)[i];
    uint2 pk;
    pk.x = (unsigned)f2b(v.x) | ((unsigned)f2b(v.y) << 16);
    pk.y = (unsigned)f2b(v.z) | ((unsigned)f2b(v.w) << 16);
    ((uint2*)xb)[i] = pk;
  }
}

// ---------- aggregation (bf16 in/out, fp32 accumulate) ----------
// one wave per node; lane owns 2 cols (one uint = 2 bf16); row = 256B coalesced.
__global__ void aggregate_bf16(const unsigned short* __restrict__ X,
                               const int* __restrict__ rowptr, const int* __restrict__ srt,
                               unsigned short* __restrict__ out, int n) {
  int w = blockIdx.x * 4 + (threadIdx.x >> 6);
  int lane = threadIdx.x & 63;
  if (w >= n) return;
  const unsigned* Xv = (const unsigned*)X;  // 64 uints per row
  unsigned u = Xv[(size_t)w * 64 + lane];
  float ax = b2f(u & 0xffff), ay = b2f(u >> 16);
  int p = rowptr[w], e = rowptr[w + 1];
  for (; p + 4 <= e; p += 4) {
    int s0 = srt[p], s1 = srt[p + 1], s2 = srt[p + 2], s3 = srt[p + 3];
    unsigned u0 = Xv[(size_t)s0 * 64 + lane];
    unsigned u1 = Xv[(size_t)s1 * 64 + lane];
    unsigned u2 = Xv[(size_t)s2 * 64 + lane];
    unsigned u3 = Xv[(size_t)s3 * 64 + lane];
    ax += b2f(u0 & 0xffff) + b2f(u1 & 0xffff) + b2f(u2 & 0xffff) + b2f(u3 & 0xffff);
    ay += b2f(u0 >> 16) + b2f(u1 >> 16) + b2f(u2 >> 16) + b2f(u3 >> 16);
  }
  for (; p < e; ++p) {
    unsigned uu = Xv[(size_t)srt[p] * 64 + lane];
    ax += b2f(uu & 0xffff);
    ay += b2f(uu >> 16);
  }
  ((unsigned*)out)[(size_t)w * 64 + lane] = (unsigned)f2b(ax) | ((unsigned)f2b(ay) << 16);
}

// ---------- fused MLP: C = (relu(A@Wa^T+ba)) @ Wb^T + bb ----------
// block = 512 thr (8 waves) x 128 rows. W tiles in LDS as bf16, XOR-swizzled
// 16B chunks: addr(row,chunk) = row*256 + ((chunk ^ (row&15)) << 4)  -> 2-way
// bank aliasing only (free). h round-trips through LDS (C-layout -> A-layout).
__device__ __forceinline__ void stage_w(char* buf, const float* __restrict__ W, int t) {
  for (int idx = t; idx < 2048; idx += 512) {  // idx = 16B-chunk id (8 bf16)
    int nrow = idx >> 4, c = idx & 15;
    float4 a = ((const float4*)W)[idx * 2];
    float4 b = ((const float4*)W)[idx * 2 + 1];
    uint4 pk;
    pk.x = (unsigned)f2b(a.x) | ((unsigned)f2b(a.y) << 16);
    pk.y = (unsigned)f2b(a.z) | ((unsigned)f2b(a.w) << 16);
    pk.z = (unsigned)f2b(b.x) | ((unsigned)f2b(b.y) << 16);
    pk.w = (unsigned)f2b(b.z) | ((unsigned)f2b(b.w) << 16);
    *(uint4*)(buf + nrow * 256 + ((c ^ (nrow & 15)) << 4)) = pk;
  }
}

template <int OUT_BF16>
__global__ __launch_bounds__(512) void mlp_kernel(
    const unsigned short* __restrict__ A, const float* __restrict__ Wa,
    const float* __restrict__ ba, const float* __restrict__ Wb,
    const float* __restrict__ bb, void* __restrict__ Cout, int n) {
  __shared__ __align__(16) char lds[65536];
  char* bufA = lds;           // Wa, later h
  char* bufB = lds + 32768;   // Wb
  int t = threadIdx.x;
  stage_w(bufA, Wa, t);
  stage_w(bufB, Wb, t);

  int wave = t >> 6, lane = t & 63;
  int m = lane & 15, q = lane >> 4;
  int rbase = blockIdx.x * 128;
  int rowA = rbase + wave * 16 + m;
  int rA = rowA < n ? rowA : (n - 1);  // clamp: garbage rows only feed guarded outputs

  // A-frags (GEMM1) from global bf16: lane holds A[m][ks*32 + q*8 .. +8]
  bf16x8 af[4];
  const bf16x8* Arow = (const bf16x8*)(A + (size_t)rA * 128);  // 16 chunks/row
#pragma unroll
  for (int ks = 0; ks < 4; ks++) af[ks] = Arow[ks * 4 + q];

  __syncthreads();  // W staged

  floatx4 acc[8];
  floatx4 zf = {0.f, 0.f, 0.f, 0.f};
#pragma unroll
  for (int j = 0; j < 8; j++) acc[j] = zf;
#pragma unroll
  for (int ks = 0; ks < 4; ks++) {
#pragma unroll
    for (int j = 0; j < 8; j++) {
      // B[k][nn] = Wa[nn][k], nn = j*16+m (nn&15 == m)
      bf16x8 bf = *(const bf16x8*)(bufA + (j * 16 + m) * 256 + (((ks * 4 + q) ^ m) << 4));
      acc[j] = __builtin_amdgcn_mfma_f32_16x16x32_bf16(af[ks], bf, acc[j], 0, 0, 0);
    }
  }
  __syncthreads();  // all waves done reading Wa

  // epilogue 1: bias+relu, write h (bf16) into bufA. D: col=lane&15, row=q*4+reg
#pragma unroll
  for (int j = 0; j < 8; j++) {
    float bias = ba[j * 16 + m];
#pragma unroll
    for (int reg = 0; reg < 4; reg++) {
      float v = fmaxf(acc[j][reg] + bias, 0.f);
      int lr = wave * 16 + q * 4 + reg;
      int col = j * 16 + m;
      *(unsigned short*)(bufA + lr * 256 + (((col >> 3) ^ (lr & 15)) << 4) + (col & 7) * 2) =
          f2b(v);
    }
  }
  __syncthreads();

  // GEMM2: A-frags from h in LDS (row lrA, lrA&15 == m)
  int lrA = wave * 16 + m;
#pragma unroll
  for (int ks = 0; ks < 4; ks++)
    af[ks] = *(const bf16x8*)(bufA + lrA * 256 + (((ks * 4 + q) ^ m) << 4));
#pragma unroll
  for (int j = 0; j < 8; j++) acc[j] = zf;
#pragma unroll
  for (int ks = 0; ks < 4; ks++) {
#pragma unroll
    for (int j = 0; j < 8; j++) {
      bf16x8 bf = *(const bf16x8*)(bufB + (j * 16 + m) * 256 + (((ks * 4 + q) ^ m) << 4));
      acc[j] = __builtin_amdgcn_mfma_f32_16x16x32_bf16(af[ks], bf, acc[j], 0, 0, 0);
    }
  }

  // epilogue 2: bias, store
#pragma unroll
  for (int j = 0; j < 8; j++) {
    float bias = bb[j * 16 + m];
#pragma unroll
    for (int reg = 0; reg < 4; reg++) {
      int row = rbase + wave * 16 + q * 4 + reg;
      if (row >= n) continue;
      float v = acc[j][reg] + bias;
      int col = j * 16 + m;
      if (OUT_BF16)
        ((unsigned short*)Cout)[(size_t)row * 128 + col] = f2b(v);
      else
        ((float*)Cout)[(size_t)row * 128 + col] = v;
    }
  }
}

extern "C" void kernel_launch(void* const* d_in, const int* in_sizes, int n_in,
                              void* d_out, int out_size, void* d_ws, size_t ws_size,
                              hipStream_t stream) {
  const float* x   = (const float*)d_in[0];
  const int*   ei  = (const int*)d_in[1];
  const float* w0a = (const float*)d_in[2];
  const float* b0a = (const float*)d_in[3];
  const float* w0b = (const float*)d_in[4];
  const float* b0b = (const float*)d_in[5];
  const float* w1a = (const float*)d_in[6];
  const float* b1a = (const float*)d_in[7];
  const float* w1b = (const float*)d_in[8];
  const float* b1b = (const float*)d_in[9];
  float* out = (float*)d_out;

  int n = in_sizes[0] / 128;  // 100000
  int E = in_sizes[1] / 2;    // 1600000
  const int* src = ei;
  const int* dst = ei + E;

  char* w = (char*)d_ws;
  int* deg = (int*)w;              w += WS_ALIGN((size_t)(n + 1) * 4);
  int* rowptr = (int*)w;           w += WS_ALIGN((size_t)(n + 1) * 4);
  int* cursor = (int*)w;           w += WS_ALIGN((size_t)(n + 1) * 4);
  int* partial = (int*)w;          w += WS_ALIGN((size_t)64 * 4);
  int* srt = (int*)w;              w += WS_ALIGN((size_t)E * 4);
  unsigned short* xb = (unsigned short*)w;  w += WS_ALIGN((size_t)n * 128 * 2);
  unsigned short* B1 = (unsigned short*)w;  // n*128 bf16

  int nb = (n + 8191) / 8192;  // 13

  // ---- CSR build ----
  hipMemsetAsync(deg, 0, (size_t)n * 4, stream);
  hist_kernel<<<(E + 255) / 256, 256, 0, stream>>>(dst, deg, E);
  scan_partial<<<nb, 1024, 0, stream>>>(deg, partial, n);
  scan_carry<<<1, 1, 0, stream>>>(partial, nb);
  scan_final<<<nb, 1024, 0, stream>>>(deg, partial, rowptr, cursor, n);
  scatter_kernel<<<(E + 255) / 256, 256, 0, stream>>>(src, dst, cursor, srt, E);

  // ---- x -> bf16 ----
  cvt_kernel<<<(n * 32 + 255) / 256, 256, 0, stream>>>(x, xb, n * 32);

  int agg_grid = (n + 3) / 4;
  int mlp_grid = (n + 127) / 128;

  // ---- layer 1 ----  (xb -> B1 -> xb)
  aggregate_bf16<<<agg_grid, 256, 0, stream>>>(xb, rowptr, srt, B1, n);
  mlp_kernel<1><<<mlp_grid, 512, 0, stream>>>(B1, w0a, b0a, w0b, b0b, xb, n);

  // ---- layer 2 ----  (xb -> B1 -> out)
  aggregate_bf16<<<agg_grid, 256, 0, stream>>>(xb, rowptr, srt, B1, n);
  mlp_kernel<0><<<mlp_grid, 512, 0, stream>>>(B1, w1a, b1a, w1b, b1b, out, n);
}

// Round 3
// 353.638 us; speedup vs baseline: 3.3830x; 1.4913x over previous
//
#include <hip/hip_runtime.h>

// GIN 2-layer, N=100000, E=1600000, D=128.
// R3: hierarchical CSR build (bucket multisplit -> per-bucket LDS counting
// sort) replaces hist/scan/global-scatter. bf16 activations, MFMA fused MLP.

typedef __attribute__((ext_vector_type(8))) short bf16x8;
typedef __attribute__((ext_vector_type(4))) float floatx4;

#define WS_ALIGN(x) (((x) + 255) & ~(size_t)255)
#define NBMAX 400   // max buckets (n <= 102400)
#define BCAP 6144   // per-bucket capacity (mean 4096, sd ~64 -> 32 sigma)

__device__ __forceinline__ unsigned short f2b(float f) {  // RTNE fp32->bf16
  unsigned u = __builtin_bit_cast(unsigned, f);
  u = (u + 0x7FFF + ((u >> 16) & 1)) >> 16;
  return (unsigned short)u;
}
__device__ __forceinline__ float b2f(unsigned u16) {  // low 16 bits = bf16
  return __builtin_bit_cast(float, u16 << 16);
}

// ---------- phase A: multisplit edges into 256-node buckets ----------
// pk = (dst&255)<<17 | src   (src < 2^17)
__global__ __launch_bounds__(256) void bucket_split(const int* __restrict__ src,
                                                    const int* __restrict__ dst,
                                                    int* __restrict__ bcnt,
                                                    unsigned* __restrict__ barr, int E, int nb) {
  __shared__ int cnt[NBMAX], base[NBMAX], cur[NBMAX];
  int t = threadIdx.x;
  for (int i = t; i < nb; i += 256) { cnt[i] = 0; cur[i] = 0; }
  __syncthreads();
  int e0 = blockIdx.x * 8192;
  int s[32], d[32];
#pragma unroll
  for (int k = 0; k < 32; k++) {
    int e = e0 + k * 256 + t;
    if (e < E) { s[k] = src[e]; d[k] = dst[e]; } else { d[k] = -1; }
  }
#pragma unroll
  for (int k = 0; k < 32; k++)
    if (d[k] >= 0) atomicAdd(&cnt[d[k] >> 8], 1);
  __syncthreads();
  for (int i = t; i < nb; i += 256) base[i] = cnt[i] ? atomicAdd(&bcnt[i], cnt[i]) : 0;
  __syncthreads();
#pragma unroll
  for (int k = 0; k < 32; k++)
    if (d[k] >= 0) {
      int b = d[k] >> 8;
      int r = atomicAdd(&cur[b], 1);
      barr[(size_t)b * BCAP + base[b] + r] = ((unsigned)(d[k] & 255) << 17) | (unsigned)s[k];
    }
}

// ---------- phase B: scan bucket counts (1 block, 512 thr) ----------
__global__ void bucket_scan(const int* __restrict__ bcnt, int* __restrict__ sbase, int nb,
                            int* __restrict__ rowptr, int n) {
  __shared__ int buf[512];
  int t = threadIdx.x;
  int v = (t < nb) ? bcnt[t] : 0;
  buf[t] = v;
  __syncthreads();
  for (int off = 1; off < 512; off <<= 1) {
    int add = (t >= off) ? buf[t - off] : 0;
    __syncthreads();
    buf[t] += add;
    __syncthreads();
  }
  if (t < nb) sbase[t] = buf[t] - v;  // exclusive
  if (t == nb - 1) { sbase[nb] = buf[t]; rowptr[n] = buf[t]; }
}

// ---------- phase C: per-bucket CSR finalize (1 block per bucket) ----------
__global__ __launch_bounds__(256) void bucket_csr(const unsigned* __restrict__ barr,
                                                  const int* __restrict__ bcnt,
                                                  const int* __restrict__ sbase,
                                                  int* __restrict__ rowptr, int* __restrict__ srt,
                                                  int n) {
  __shared__ int cnt[256], off[256], off2[256];
  int b = blockIdx.x, t = threadIdx.x;
  int cb = bcnt[b];
  int node0 = b * 256;
  int nlocal = min(256, n - node0);
  cnt[t] = 0;
  off2[t] = 0;
  __syncthreads();
  const unsigned* bp = barr + (size_t)b * BCAP;
  for (int i = t; i < cb; i += 256) atomicAdd(&cnt[bp[i] >> 17], 1);
  __syncthreads();
  int v = cnt[t];
  off[t] = v;
  __syncthreads();
  for (int o = 1; o < 256; o <<= 1) {
    int add = (t >= o) ? off[t - o] : 0;
    __syncthreads();
    off[t] += add;
    __syncthreads();
  }
  int excl = off[t] - v;  // exclusive prefix within bucket
  int sb = sbase[b];
  if (t < nlocal) rowptr[node0 + t] = sb + excl;
  cnt[t] = excl;  // reuse as scatter base
  __syncthreads();
  for (int i = t; i < cb; i += 256) {
    unsigned pk = bp[i];
    int local = pk >> 17;
    int r = atomicAdd(&off2[local], 1);
    srt[sb + cnt[local] + r] = pk & 0x1FFFF;
  }
}

// ---------- fp32 -> bf16 convert ----------
__global__ void cvt_kernel(const float* __restrict__ x, unsigned short* __restrict__ xb, int n4) {
  int i = blockIdx.x * blockDim.x + threadIdx.x;
  if (i < n4) {
    float4 v = ((const float4*)x)[i];
    uint2 pk;
    pk.x = (unsigned)f2b(v.x) | ((unsigned)f2b(v.y) << 16);
    pk.y = (unsigned)f2b(v.z) | ((unsigned)f2b(v.w) << 16);
    ((uint2*)xb)[i] = pk;
  }
}

// ---------- aggregation (bf16 in/out, fp32 accumulate) ----------
__global__ void aggregate_bf16(const unsigned short* __restrict__ X,
                               const int* __restrict__ rowptr, const int* __restrict__ srt,
                               unsigned short* __restrict__ out, int n) {
  int w = blockIdx.x * 4 + (threadIdx.x >> 6);
  int lane = threadIdx.x & 63;
  if (w >= n) return;
  const unsigned* Xv = (const unsigned*)X;  // 64 uints per row
  unsigned u = Xv[(size_t)w * 64 + lane];
  float ax = b2f(u & 0xffff), ay = b2f(u >> 16);
  int p = rowptr[w], e = rowptr[w + 1];
  for (; p + 4 <= e; p += 4) {
    int s0 = srt[p], s1 = srt[p + 1], s2 = srt[p + 2], s3 = srt[p + 3];
    unsigned u0 = Xv[(size_t)s0 * 64 + lane];
    unsigned u1 = Xv[(size_t)s1 * 64 + lane];
    unsigned u2 = Xv[(size_t)s2 * 64 + lane];
    unsigned u3 = Xv[(size_t)s3 * 64 + lane];
    ax += b2f(u0 & 0xffff) + b2f(u1 & 0xffff) + b2f(u2 & 0xffff) + b2f(u3 & 0xffff);
    ay += b2f(u0 >> 16) + b2f(u1 >> 16) + b2f(u2 >> 16) + b2f(u3 >> 16);
  }
  for (; p < e; ++p) {
    unsigned uu = Xv[(size_t)srt[p] * 64 + lane];
    ax += b2f(uu & 0xffff);
    ay += b2f(uu >> 16);
  }
  ((unsigned*)out)[(size_t)w * 64 + lane] = (unsigned)f2b(ax) | ((unsigned)f2b(ay) << 16);
}

// ---------- fused MLP: C = (relu(A@Wa^T+ba)) @ Wb^T + bb ----------
__device__ __forceinline__ void stage_w(char* buf, const float* __restrict__ W, int t) {
  for (int idx = t; idx < 2048; idx += 512) {  // idx = 16B-chunk id (8 bf16)
    int nrow = idx >> 4, c = idx & 15;
    float4 a = ((const float4*)W)[idx * 2];
    float4 b = ((const float4*)W)[idx * 2 + 1];
    uint4 pk;
    pk.x = (unsigned)f2b(a.x) | ((unsigned)f2b(a.y) << 16);
    pk.y = (unsigned)f2b(a.z) | ((unsigned)f2b(a.w) << 16);
    pk.z = (unsigned)f2b(b.x) | ((unsigned)f2b(b.y) << 16);
    pk.w = (unsigned)f2b(b.z) | ((unsigned)f2b(b.w) << 16);
    *(uint4*)(buf + nrow * 256 + ((c ^ (nrow & 15)) << 4)) = pk;
  }
}

template <int OUT_BF16>
__global__ __launch_bounds__(512) void mlp_kernel(
    const unsigned short* __restrict__ A, const float* __restrict__ Wa,
    const float* __restrict__ ba, const float* __restrict__ Wb,
    const float* __restrict__ bb, void* __restrict__ Cout, int n) {
  __shared__ __align__(16) char lds[65536];
  char* bufA = lds;          // Wa, later h
  char* bufB = lds + 32768;  // Wb
  int t = threadIdx.x;
  stage_w(bufA, Wa, t);
  stage_w(bufB, Wb, t);

  int wave = t >> 6, lane = t & 63;
  int m = lane & 15, q = lane >> 4;
  int rbase = blockIdx.x * 128;
  int rowA = rbase + wave * 16 + m;
  int rA = rowA < n ? rowA : (n - 1);

  bf16x8 af[4];
  const bf16x8* Arow = (const bf16x8*)(A + (size_t)rA * 128);
#pragma unroll
  for (int ks = 0; ks < 4; ks++) af[ks] = Arow[ks * 4 + q];

  __syncthreads();

  floatx4 acc[8];
  floatx4 zf = {0.f, 0.f, 0.f, 0.f};
#pragma unroll
  for (int j = 0; j < 8; j++) acc[j] = zf;
#pragma unroll
  for (int ks = 0; ks < 4; ks++) {
#pragma unroll
    for (int j = 0; j < 8; j++) {
      bf16x8 bf = *(const bf16x8*)(bufA + (j * 16 + m) * 256 + (((ks * 4 + q) ^ m) << 4));
      acc[j] = __builtin_amdgcn_mfma_f32_16x16x32_bf16(af[ks], bf, acc[j], 0, 0, 0);
    }
  }
  __syncthreads();

#pragma unroll
  for (int j = 0; j < 8; j++) {
    float bias = ba[j * 16 + m];
#pragma unroll
    for (int reg = 0; reg < 4; reg++) {
      float v = fmaxf(acc[j][reg] + bias, 0.f);
      int lr = wave * 16 + q * 4 + reg;
      int col = j * 16 + m;
      *(unsigned short*)(bufA + lr * 256 + (((col >> 3) ^ (lr & 15)) << 4) + (col & 7) * 2) =
          f2b(v);
    }
  }
  __syncthreads();

  int lrA = wave * 16 + m;
#pragma unroll
  for (int ks = 0; ks < 4; ks++)
    af[ks] = *(const bf16x8*)(bufA + lrA * 256 + (((ks * 4 + q) ^ m) << 4));
#pragma unroll
  for (int j = 0; j < 8; j++) acc[j] = zf;
#pragma unroll
  for (int ks = 0; ks < 4; ks++) {
#pragma unroll
    for (int j = 0; j < 8; j++) {
      bf16x8 bf = *(const bf16x8*)(bufB + (j * 16 + m) * 256 + (((ks * 4 + q) ^ m) << 4));
      acc[j] = __builtin_amdgcn_mfma_f32_16x16x32_bf16(af[ks], bf, acc[j], 0, 0, 0);
    }
  }

#pragma unroll
  for (int j = 0; j < 8; j++) {
    float bias = bb[j * 16 + m];
#pragma unroll
    for (int reg = 0; reg < 4; reg++) {
      int row = rbase + wave * 16 + q * 4 + reg;
      if (row >= n) continue;
      float v = acc[j][reg] + bias;
      int col = j * 16 + m;
      if (OUT_BF16)
        ((unsigned short*)Cout)[(size_t)row * 128 + col] = f2b(v);
      else
        ((float*)Cout)[(size_t)row * 128 + col] = v;
    }
  }
}

extern "C" void kernel_launch(void* const* d_in, const int* in_sizes, int n_in,
                              void* d_out, int out_size, void* d_ws, size_t ws_size,
                              hipStream_t stream) {
  const float* x   = (const float*)d_in[0];
  const int*   ei  = (const int*)d_in[1];
  const float* w0a = (const float*)d_in[2];
  const float* b0a = (const float*)d_in[3];
  const float* w0b = (const float*)d_in[4];
  const float* b0b = (const float*)d_in[5];
  const float* w1a = (const float*)d_in[6];
  const float* b1a = (const float*)d_in[7];
  const float* w1b = (const float*)d_in[8];
  const float* b1b = (const float*)d_in[9];
  float* out = (float*)d_out;

  int n = in_sizes[0] / 128;  // 100000
  int E = in_sizes[1] / 2;    // 1600000
  const int* src = ei;
  const int* dst = ei + E;
  int nb = (n + 255) / 256;  // 391

  char* w = (char*)d_ws;
  int* rowptr = (int*)w;           w += WS_ALIGN((size_t)(n + 1) * 4);
  int* sbase = (int*)w;            w += WS_ALIGN((size_t)(NBMAX + 1) * 4);
  int* bcnt = (int*)w;             w += WS_ALIGN((size_t)NBMAX * 4);
  int* srt = (int*)w;              w += WS_ALIGN((size_t)E * 4);
  unsigned short* xb = (unsigned short*)w;  w += WS_ALIGN((size_t)n * 128 * 2);
  // barr (nb*BCAP uints, ~9.6MB) overlaps B1 (n*128 bf16): barr is dead
  // before the first aggregate writes B1.
  unsigned* barr = (unsigned*)w;
  unsigned short* B1 = (unsigned short*)w;

  // ---- CSR build (hierarchical) ----
  hipMemsetAsync(bcnt, 0, (size_t)nb * 4, stream);
  bucket_split<<<(E + 8191) / 8192, 256, 0, stream>>>(src, dst, bcnt, barr, E, nb);
  bucket_scan<<<1, 512, 0, stream>>>(bcnt, sbase, nb, rowptr, n);
  bucket_csr<<<nb, 256, 0, stream>>>(barr, bcnt, sbase, rowptr, srt, n);

  // ---- x -> bf16 ----
  cvt_kernel<<<(n * 32 + 255) / 256, 256, 0, stream>>>(x, xb, n * 32);

  int agg_grid = (n + 3) / 4;
  int mlp_grid = (n + 127) / 128;

  // ---- layer 1 ----  (xb -> B1 -> xb)
  aggregate_bf16<<<agg_grid, 256, 0, stream>>>(xb, rowptr, srt, B1, n);
  mlp_kernel<1><<<mlp_grid, 512, 0, stream>>>(B1, w0a, b0a, w0b, b0b, xb, n);

  // ---- layer 2 ----  (xb -> B1 -> out)
  aggregate_bf16<<<agg_grid, 256, 0, stream>>>(xb, rowptr, srt, B1, n);
  mlp_kernel<0><<<mlp_grid, 512, 0, stream>>>(B1, w1a, b1a, w1b, b1b, out, n);
}